// Round 7
// baseline (159.112 us; speedup 1.0000x reference)
//
#include <hip/hip_runtime.h>
#include <hip/hip_fp16.h>

#define Bsz 8
#define Cn  4
#define Hn  64
#define Wn  2048
#define HW  (Hn*Wn)

#define TW 64
#define TH 8
#define BLK 256
// 3-iteration cone: +/-3 rows, +/-6 cols
#define BW 76
#define BH 14
#define NB (BW*BH)          // 1064
// region-1 (iter-1 output region): 72 x 12 at tile-local (-2,-4)
#define R1W 72
#define R1H 12
#define NP1 (R1W*(R1H/2))   // 432 vertical pixel-pairs

// Gaussian stencil exp(-(dh^2+dw^2)/(2*0.9^2)), center zeroed.
#define G1 0.53940824f
#define G2 0.29096127f
#define G4 0.08465836f
#define G5 0.04566536f

struct Half4 { __half2 lo, hi; };
struct Beta { __half2 t[14]; __half2 mk; };   // (px0,px1) packed per tap

__device__ __forceinline__ float Gw(int r, int d) {
    const float Gt[3][5] = {{G5,G2,G1,G2,G5},{G4,G1,0.f,G1,G4},{G5,G2,G1,G2,G5}};
    return Gt[r][d];
}
__device__ __forceinline__ constexpr int tap_of(int r, int d) {
    return (r == 0) ? d : (r == 1) ? ((d < 2) ? 5 + d : 4 + d) : 9 + d;
}

// beta*mask tap weights for one vertical pixel-pair, from staged (xyz,mask).
__device__ __forceinline__ void compute_beta(int pair, const float4* __restrict__ X,
                                             Beta& B) {
    const int pr = pair / R1W;
    const int pc = pair - pr * R1W;
    const int bx0 = (2 * pr + 1) * BW + pc + 2;
    const float4 xc0 = X[bx0];
    const float4 xc1 = X[bx0 + BW];
    float bm0[14], bm1[14];
#pragma unroll
    for (int j = 0; j < 4; ++j) {
        const int rb = bx0 + (j - 1) * BW;
#pragma unroll
        for (int d = 0; d < 5; ++d) {
            const float4 xn = X[rb + d - 2];
            if (j <= 2 && !(j == 1 && d == 2)) {
                float dx = xn.x - xc0.x, dy = xn.y - xc0.y, dz = xn.z - xc0.z;
                bm0[tap_of(j, d)] = __expf(-2222.2222f * (dx*dx + dy*dy + dz*dz)) * xn.w;
            }
            if (j >= 1 && !(j == 2 && d == 2)) {
                float dx = xn.x - xc1.x, dy = xn.y - xc1.y, dz = xn.z - xc1.z;
                bm1[tap_of(j - 1, d)] = __expf(-2222.2222f * (dx*dx + dy*dy + dz*dz)) * xn.w;
            }
        }
    }
#pragma unroll
    for (int t = 0; t < 14; ++t) B.t[t] = __floats2half2_rn(bm0[t], bm1[t]);
    B.mk = __floats2half2_rn(xc0.w, xc1.w);
}

template<bool FINAL>
__device__ __forceinline__ void finish_one(int gh, int gw, int bi,
        __half2 ka, __half2 kb, __half2 aa, __half2 ab, float mc,
        const float* __restrict__ unary, float* __restrict__ outp,
        Half4* __restrict__ Sout, size_t qbase,
        const float* wa, const float* wsm, const float* cw, bool store_ok) {
    if (FINAL && !store_ok) return;
    const bool inimg = FINAL || ((gh >= 0) & (gh < Hn) & (gw >= 0) & (gw < Wn));
    if (inimg) {
        size_t p = (size_t)gh * Wn + gw;
        float ksm[4] = {__low2float(ka), __high2float(ka), __low2float(kb), __high2float(kb)};
        float app[4] = {__low2float(aa), __high2float(aa), __low2float(ab), __high2float(ab)};
        float wk[4];
#pragma unroll
        for (int c = 0; c < 4; ++c)
            wk[c] = ksm[c] * (wsm[c] + wa[c] * (app[c] * mc));
        float q[4];
#pragma unroll
        for (int o = 0; o < 4; ++o) {
            float pw = cw[o*4+0]*wk[0] + cw[o*4+1]*wk[1] + cw[o*4+2]*wk[2] + cw[o*4+3]*wk[3];
            q[o] = unary[qbase + p + (size_t)o * HW] - pw;
        }
        if (FINAL) {
#pragma unroll
            for (int o = 0; o < 4; ++o)
                outp[qbase + p + (size_t)o * HW] = q[o];
        } else {
            float mx = fmaxf(fmaxf(q[0], q[1]), fmaxf(q[2], q[3]));
            float e0 = __expf(q[0]-mx), e1 = __expf(q[1]-mx);
            float e2 = __expf(q[2]-mx), e3 = __expf(q[3]-mx);
            float inv = 1.0f / (e0 + e1 + e2 + e3);
            Half4 s; s.lo = __floats2half2_rn(e0*inv, e1*inv);
            s.hi = __floats2half2_rn(e2*inv, e3*inv);
            Sout[bi] = s;
        }
    } else if (!FINAL) {
        Half4 z; z.lo = __float2half2_rn(0.f); z.hi = z.lo;
        Sout[bi] = z;
    }
}

template<bool FINAL>
__device__ __forceinline__ void do_pair(int pair, const Half4* __restrict__ Sin,
        Half4* __restrict__ Sout, const Beta& B,
        const float* __restrict__ unary, float* __restrict__ outp,
        size_t qbase, int h0, int w0,
        const float* wa, const float* wsm, const float* cw) {
    const int pr = pair / R1W;
    const int pc = pair - pr * R1W;
    const int bx0 = (2 * pr + 1) * BW + pc + 2;

    const __half2 z2 = __float2half2_rn(0.f);
    __half2 k0a=z2,k0b=z2,a0a=z2,a0b=z2,k1a=z2,k1b=z2,a1a=z2,a1b=z2;

#pragma unroll
    for (int j = 0; j < 4; ++j) {
        const int rb = bx0 + (j - 1) * BW;
        Half4 s[5];
#pragma unroll
        for (int d = 0; d < 5; ++d) s[d] = Sin[rb + d - 2];
#pragma unroll
        for (int d = 0; d < 5; ++d) {
            if (j <= 2 && !(j == 1 && d == 2)) {          // px0: dh = j-1
                const int t = tap_of(j, d);
                const __half2 g2 = __float2half2_rn(Gw(j, d));
                k0a = __hfma2(g2, s[d].lo, k0a);
                k0b = __hfma2(g2, s[d].hi, k0b);
                const __half2 bm2 = __half2half2(__low2half(B.t[t]));
                a0a = __hfma2(bm2, s[d].lo, a0a);
                a0b = __hfma2(bm2, s[d].hi, a0b);
            }
            if (j >= 1 && !(j == 2 && d == 2)) {          // px1: dh = j-2
                const int t = tap_of(j - 1, d);
                const __half2 g2 = __float2half2_rn(Gw(j - 1, d));
                k1a = __hfma2(g2, s[d].lo, k1a);
                k1b = __hfma2(g2, s[d].hi, k1b);
                const __half2 bm2 = __half2half2(__high2half(B.t[t]));
                a1a = __hfma2(bm2, s[d].lo, a1a);
                a1b = __hfma2(bm2, s[d].hi, a1b);
            }
        }
    }

    const int gw = w0 + pc - 4;
    const int gh0 = h0 + 2 * pr - 2;
    // region-3 (stored tile): rows 0..7 -> pr in [1,4]; cols 0..63 -> pc in [4,67]
    const bool ok = (pr >= 1) & (pr <= 4) & (pc >= 4) & (pc <= 67);
    finish_one<FINAL>(gh0,     gw, bx0,      k0a, k0b, a0a, a0b, __low2float(B.mk),
                      unary, outp, Sout, qbase, wa, wsm, cw, ok);
    finish_one<FINAL>(gh0 + 1, gw, bx0 + BW, k1a, k1b, a1a, a1b, __high2float(B.mk),
                      unary, outp, Sout, qbase, wa, wsm, cw, ok);
}

__global__ __launch_bounds__(BLK, 4) void crf_fused(const float* __restrict__ unary,
                                                    const float* __restrict__ xyz,
                                                    const float* __restrict__ mask,
                                                    const float* __restrict__ wa_g,
                                                    const float* __restrict__ wsm_g,
                                                    const float* __restrict__ cw_g,
                                                    float* __restrict__ outp) {
    __shared__ __align__(16) unsigned char LDS_[NB * 16];   // 17024 B
    Half4*  SA   = (Half4*)LDS_;                // [0, NB*8)
    Half4*  SB   = (Half4*)(LDS_ + NB * 8);     // [NB*8, NB*16)
    float4* XBUF = (float4*)LDS_;               // overlays SA+SB, phases 1-2 only

    const int tid = threadIdx.x;
    const int w0 = blockIdx.x * TW;
    const int h0 = blockIdx.y * TH;
    const int b  = blockIdx.z;

    const size_t qbase = (size_t)b * Cn * HW;
    const size_t xbase = (size_t)b * 3 * HW;
    const size_t mbase = (size_t)b * HW;

    float wa[4], wsm[4], cw[16];
#pragma unroll
    for (int k = 0; k < 4; ++k) { wa[k] = wa_g[k]; wsm[k] = wsm_g[k]; }
#pragma unroll
    for (int k = 0; k < 16; ++k) cw[k] = cw_g[k];

    // ---- phase 1: stage packed (xyz, mask) cone halo into XBUF ----
    for (int i = tid; i < NB; i += BLK) {
        int br = i / BW, bc = i - br * BW;
        int gh = h0 + br - 3, gw = w0 + bc - 6;
        float4 xm = make_float4(0.f, 0.f, 0.f, 0.f);
        if (gh >= 0 && gh < Hn && gw >= 0 && gw < Wn) {
            size_t p = (size_t)gh * Wn + gw;
            xm = make_float4(xyz[xbase + p], xyz[xbase + p + HW],
                             xyz[xbase + p + 2 * HW], mask[mbase + p]);
        }
        XBUF[i] = xm;
    }
    __syncthreads();

    // ---- phase 2: iteration-invariant beta*mask into REGISTERS ----
    Beta B0, B1;
    compute_beta(tid, XBUF, B0);
    const bool t2 = tid < (NP1 - BLK);          // 176 threads take a 2nd pair
    if (t2) compute_beta(tid + BLK, XBUF, B1);
    __syncthreads();

    // ---- phase 3: SA = softmax(unary) staged fp16x4 over NB; SB ring-zeroed ----
    for (int i = tid; i < NB; i += BLK) {
        int br = i / BW, bc = i - br * BW;
        int gh = h0 + br - 3, gw = w0 + bc - 6;
        Half4 s; s.lo = __float2half2_rn(0.f); s.hi = s.lo;
        if (gh >= 0 && gh < Hn && gw >= 0 && gw < Wn) {
            size_t p = (size_t)gh * Wn + gw;
            float q0 = unary[qbase + p];
            float q1 = unary[qbase + p + HW];
            float q2 = unary[qbase + p + 2 * HW];
            float q3 = unary[qbase + p + 3 * HW];
            float mx = fmaxf(fmaxf(q0, q1), fmaxf(q2, q3));
            float e0 = __expf(q0 - mx), e1 = __expf(q1 - mx);
            float e2 = __expf(q2 - mx), e3 = __expf(q3 - mx);
            float inv = 1.0f / (e0 + e1 + e2 + e3);
            s.lo = __floats2half2_rn(e0 * inv, e1 * inv);
            s.hi = __floats2half2_rn(e2 * inv, e3 * inv);
        }
        SA[i] = s;
        Half4 z; z.lo = __float2half2_rn(0.f); z.hi = z.lo;
        SB[i] = z;
    }
    __syncthreads();

    // ---- iter 1: SA -> SB (fixed pixel ownership, full region-1) ----
    do_pair<false>(tid, SA, SB, B0, unary, nullptr, qbase, h0, w0, wa, wsm, cw);
    if (t2) do_pair<false>(tid + BLK, SA, SB, B1, unary, nullptr, qbase, h0, w0, wa, wsm, cw);
    __syncthreads();
    // ---- iter 2: SB -> SA ----
    do_pair<false>(tid, SB, SA, B0, unary, nullptr, qbase, h0, w0, wa, wsm, cw);
    if (t2) do_pair<false>(tid + BLK, SB, SA, B1, unary, nullptr, qbase, h0, w0, wa, wsm, cw);
    __syncthreads();
    // ---- iter 3: SA -> out (store only region-3 == the tile) ----
    do_pair<true>(tid, SA, nullptr, B0, unary, outp, qbase, h0, w0, wa, wsm, cw);
    if (t2) do_pair<true>(tid + BLK, SA, nullptr, B1, unary, outp, qbase, h0, w0, wa, wsm, cw);
}

extern "C" void kernel_launch(void* const* d_in, const int* in_sizes, int n_in,
                              void* d_out, int out_size, void* d_ws, size_t ws_size,
                              hipStream_t stream) {
    const float* unary  = (const float*)d_in[0];
    const float* xyz    = (const float*)d_in[1];
    const float* mask   = (const float*)d_in[2];
    const float* wa     = (const float*)d_in[3];
    const float* wsm    = (const float*)d_in[4];
    const float* compat = (const float*)d_in[5];
    float* outp = (float*)d_out;

    dim3 grid(Wn / TW, Hn / TH, Bsz), blk(BLK);
    crf_fused<<<grid, blk, 0, stream>>>(unary, xyz, mask, wa, wsm, compat, outp);
}

// Round 8
// 133.712 us; speedup vs baseline: 1.1900x; 1.1900x over previous
//
#include <hip/hip_runtime.h>
#include <hip/hip_fp16.h>

#define Bsz 8
#define Cn  4
#define Hn  64
#define Wn  2048
#define HW  (Hn*Wn)

#define TW 64
#define TH 8
#define BLK 256
// 3-iteration cone: +/-3 rows, +/-6 cols
#define BW 76
#define BH 14
#define NB (BW*BH)          // 1064
// region-1 (iter-1 output region): 72 x 12 at tile-local (-2,-4)
#define R1W 72
#define R1H 12
#define NP1 (R1W*(R1H/2))   // 432 vertical pixel-pairs

// Gaussian stencil exp(-(dh^2+dw^2)/(2*0.9^2)), center zeroed.
#define G1 0.53940824f
#define G2 0.29096127f
#define G4 0.08465836f
#define G5 0.04566536f

struct Half4 { __half2 lo, hi; };
struct Beta { __half2 t[14]; __half2 mk; };   // (px0,px1) packed per tap

__device__ __forceinline__ float Gw(int r, int d) {
    const float Gt[3][5] = {{G5,G2,G1,G2,G5},{G4,G1,0.f,G1,G4},{G5,G2,G1,G2,G5}};
    return Gt[r][d];
}
__device__ __forceinline__ constexpr int tap_of(int r, int d) {
    return (r == 0) ? d : (r == 1) ? ((d < 2) ? 5 + d : 4 + d) : 9 + d;
}

// beta*mask tap weights for one vertical pixel-pair, from staged (xyz,mask).
__device__ __forceinline__ void compute_beta(int pair, const float4* __restrict__ X,
                                             Beta& B) {
    const int pr = pair / R1W;
    const int pc = pair - pr * R1W;
    const int bx0 = (2 * pr + 1) * BW + pc + 2;
    const float4 xc0 = X[bx0];
    const float4 xc1 = X[bx0 + BW];
    float bm0[14], bm1[14];
#pragma unroll
    for (int j = 0; j < 4; ++j) {
        const int rb = bx0 + (j - 1) * BW;
#pragma unroll
        for (int d = 0; d < 5; ++d) {
            const float4 xn = X[rb + d - 2];
            if (j <= 2 && !(j == 1 && d == 2)) {
                float dx = xn.x - xc0.x, dy = xn.y - xc0.y, dz = xn.z - xc0.z;
                bm0[tap_of(j, d)] = __expf(-2222.2222f * (dx*dx + dy*dy + dz*dz)) * xn.w;
            }
            if (j >= 1 && !(j == 2 && d == 2)) {
                float dx = xn.x - xc1.x, dy = xn.y - xc1.y, dz = xn.z - xc1.z;
                bm1[tap_of(j - 1, d)] = __expf(-2222.2222f * (dx*dx + dy*dy + dz*dz)) * xn.w;
            }
        }
    }
#pragma unroll
    for (int t = 0; t < 14; ++t) B.t[t] = __floats2half2_rn(bm0[t], bm1[t]);
    B.mk = __floats2half2_rn(xc0.w, xc1.w);
}

template<bool FINAL>
__device__ __forceinline__ void finish_one(int gh, int gw, int bi,
        __half2 ka, __half2 kb, __half2 aa, __half2 ab, float mc,
        const float* __restrict__ unary, float* __restrict__ outp,
        Half4* __restrict__ Sout, size_t qbase,
        const float* wa, const float* wsm, const float* cw, bool store_ok) {
    if (FINAL && !store_ok) return;
    const bool inimg = FINAL || ((gh >= 0) & (gh < Hn) & (gw >= 0) & (gw < Wn));
    if (inimg) {
        size_t p = (size_t)gh * Wn + gw;
        float ksm[4] = {__low2float(ka), __high2float(ka), __low2float(kb), __high2float(kb)};
        float app[4] = {__low2float(aa), __high2float(aa), __low2float(ab), __high2float(ab)};
        float wk[4];
#pragma unroll
        for (int c = 0; c < 4; ++c)
            wk[c] = ksm[c] * (wsm[c] + wa[c] * (app[c] * mc));
        float q[4];
#pragma unroll
        for (int o = 0; o < 4; ++o) {
            float pw = cw[o*4+0]*wk[0] + cw[o*4+1]*wk[1] + cw[o*4+2]*wk[2] + cw[o*4+3]*wk[3];
            q[o] = unary[qbase + p + (size_t)o * HW] - pw;
        }
        if (FINAL) {
#pragma unroll
            for (int o = 0; o < 4; ++o)
                outp[qbase + p + (size_t)o * HW] = q[o];
        } else {
            float mx = fmaxf(fmaxf(q[0], q[1]), fmaxf(q[2], q[3]));
            float e0 = __expf(q[0]-mx), e1 = __expf(q[1]-mx);
            float e2 = __expf(q[2]-mx), e3 = __expf(q[3]-mx);
            float inv = 1.0f / (e0 + e1 + e2 + e3);
            Half4 s; s.lo = __floats2half2_rn(e0*inv, e1*inv);
            s.hi = __floats2half2_rn(e2*inv, e3*inv);
            Sout[bi] = s;
        }
    } else if (!FINAL) {
        Half4 z; z.lo = __float2half2_rn(0.f); z.hi = z.lo;
        Sout[bi] = z;
    }
}

template<bool FINAL>
__device__ __forceinline__ void do_pair(int pair, const Half4* __restrict__ Sin,
        Half4* __restrict__ Sout, const Beta& B,
        const float* __restrict__ unary, float* __restrict__ outp,
        size_t qbase, int h0, int w0,
        const float* wa, const float* wsm, const float* cw) {
    const int pr = pair / R1W;
    const int pc = pair - pr * R1W;
    const int bx0 = (2 * pr + 1) * BW + pc + 2;

    const __half2 z2 = __float2half2_rn(0.f);
    __half2 k0a=z2,k0b=z2,a0a=z2,a0b=z2,k1a=z2,k1b=z2,a1a=z2,a1b=z2;

#pragma unroll
    for (int j = 0; j < 4; ++j) {
        const int rb = bx0 + (j - 1) * BW;
        Half4 s[5];
#pragma unroll
        for (int d = 0; d < 5; ++d) s[d] = Sin[rb + d - 2];
#pragma unroll
        for (int d = 0; d < 5; ++d) {
            if (j <= 2 && !(j == 1 && d == 2)) {          // px0: dh = j-1
                const int t = tap_of(j, d);
                const __half2 g2 = __float2half2_rn(Gw(j, d));
                k0a = __hfma2(g2, s[d].lo, k0a);
                k0b = __hfma2(g2, s[d].hi, k0b);
                const __half2 bm2 = __half2half2(__low2half(B.t[t]));
                a0a = __hfma2(bm2, s[d].lo, a0a);
                a0b = __hfma2(bm2, s[d].hi, a0b);
            }
            if (j >= 1 && !(j == 2 && d == 2)) {          // px1: dh = j-2
                const int t = tap_of(j - 1, d);
                const __half2 g2 = __float2half2_rn(Gw(j - 1, d));
                k1a = __hfma2(g2, s[d].lo, k1a);
                k1b = __hfma2(g2, s[d].hi, k1b);
                const __half2 bm2 = __half2half2(__high2half(B.t[t]));
                a1a = __hfma2(bm2, s[d].lo, a1a);
                a1b = __hfma2(bm2, s[d].hi, a1b);
            }
        }
    }

    const int gw = w0 + pc - 4;
    const int gh0 = h0 + 2 * pr - 2;
    // region-3 (stored tile): rows 0..7 -> pr in [1,4]; cols 0..63 -> pc in [4,67]
    const bool ok = (pr >= 1) & (pr <= 4) & (pc >= 4) & (pc <= 67);
    finish_one<FINAL>(gh0,     gw, bx0,      k0a, k0b, a0a, a0b, __low2float(B.mk),
                      unary, outp, Sout, qbase, wa, wsm, cw, ok);
    finish_one<FINAL>(gh0 + 1, gw, bx0 + BW, k1a, k1b, a1a, a1b, __high2float(B.mk),
                      unary, outp, Sout, qbase, wa, wsm, cw, ok);
}

// NOTE: no min-waves arg — (BLK,4) and (512,4) clamp VGPRs to 64 and spill
// ~190 MB of scratch traffic (rounds 6-7). Natural allocation is ~110 VGPR.
__global__ __launch_bounds__(BLK) void crf_fused(const float* __restrict__ unary,
                                                 const float* __restrict__ xyz,
                                                 const float* __restrict__ mask,
                                                 const float* __restrict__ wa_g,
                                                 const float* __restrict__ wsm_g,
                                                 const float* __restrict__ cw_g,
                                                 float* __restrict__ outp) {
    __shared__ __align__(16) unsigned char LDS_[NB * 16];   // 17024 B
    Half4*  SA   = (Half4*)LDS_;                // [0, NB*8)
    Half4*  SB   = (Half4*)(LDS_ + NB * 8);     // [NB*8, NB*16)
    float4* XBUF = (float4*)LDS_;               // overlays SA+SB, phases 1-2 only

    const int tid = threadIdx.x;
    const int w0 = blockIdx.x * TW;
    const int h0 = blockIdx.y * TH;
    const int b  = blockIdx.z;

    const size_t qbase = (size_t)b * Cn * HW;
    const size_t xbase = (size_t)b * 3 * HW;
    const size_t mbase = (size_t)b * HW;

    float wa[4], wsm[4], cw[16];
#pragma unroll
    for (int k = 0; k < 4; ++k) { wa[k] = wa_g[k]; wsm[k] = wsm_g[k]; }
#pragma unroll
    for (int k = 0; k < 16; ++k) cw[k] = cw_g[k];

    // ---- phase 1: stage packed (xyz, mask) cone halo into XBUF ----
    for (int i = tid; i < NB; i += BLK) {
        int br = i / BW, bc = i - br * BW;
        int gh = h0 + br - 3, gw = w0 + bc - 6;
        float4 xm = make_float4(0.f, 0.f, 0.f, 0.f);
        if (gh >= 0 && gh < Hn && gw >= 0 && gw < Wn) {
            size_t p = (size_t)gh * Wn + gw;
            xm = make_float4(xyz[xbase + p], xyz[xbase + p + HW],
                             xyz[xbase + p + 2 * HW], mask[mbase + p]);
        }
        XBUF[i] = xm;
    }
    __syncthreads();

    // ---- phase 2: iteration-invariant beta*mask into REGISTERS ----
    Beta B0, B1;
    compute_beta(tid, XBUF, B0);
    const bool t2 = tid < (NP1 - BLK);          // 176 threads take a 2nd pair
    if (t2) compute_beta(tid + BLK, XBUF, B1);
    __syncthreads();

    // ---- phase 3: SA = softmax(unary) staged fp16x4 over NB; SB ring-zeroed ----
    for (int i = tid; i < NB; i += BLK) {
        int br = i / BW, bc = i - br * BW;
        int gh = h0 + br - 3, gw = w0 + bc - 6;
        Half4 s; s.lo = __float2half2_rn(0.f); s.hi = s.lo;
        if (gh >= 0 && gh < Hn && gw >= 0 && gw < Wn) {
            size_t p = (size_t)gh * Wn + gw;
            float q0 = unary[qbase + p];
            float q1 = unary[qbase + p + HW];
            float q2 = unary[qbase + p + 2 * HW];
            float q3 = unary[qbase + p + 3 * HW];
            float mx = fmaxf(fmaxf(q0, q1), fmaxf(q2, q3));
            float e0 = __expf(q0 - mx), e1 = __expf(q1 - mx);
            float e2 = __expf(q2 - mx), e3 = __expf(q3 - mx);
            float inv = 1.0f / (e0 + e1 + e2 + e3);
            s.lo = __floats2half2_rn(e0 * inv, e1 * inv);
            s.hi = __floats2half2_rn(e2 * inv, e3 * inv);
        }
        SA[i] = s;
        Half4 z; z.lo = __float2half2_rn(0.f); z.hi = z.lo;
        SB[i] = z;
    }
    __syncthreads();

    // ---- iter 1: SA -> SB (fixed pixel ownership, full region-1) ----
    do_pair<false>(tid, SA, SB, B0, unary, nullptr, qbase, h0, w0, wa, wsm, cw);
    if (t2) do_pair<false>(tid + BLK, SA, SB, B1, unary, nullptr, qbase, h0, w0, wa, wsm, cw);
    __syncthreads();
    // ---- iter 2: SB -> SA ----
    do_pair<false>(tid, SB, SA, B0, unary, nullptr, qbase, h0, w0, wa, wsm, cw);
    if (t2) do_pair<false>(tid + BLK, SB, SA, B1, unary, nullptr, qbase, h0, w0, wa, wsm, cw);
    __syncthreads();
    // ---- iter 3: SA -> out (store only region-3 == the tile) ----
    do_pair<true>(tid, SA, nullptr, B0, unary, outp, qbase, h0, w0, wa, wsm, cw);
    if (t2) do_pair<true>(tid + BLK, SA, nullptr, B1, unary, outp, qbase, h0, w0, wa, wsm, cw);
}

extern "C" void kernel_launch(void* const* d_in, const int* in_sizes, int n_in,
                              void* d_out, int out_size, void* d_ws, size_t ws_size,
                              hipStream_t stream) {
    const float* unary  = (const float*)d_in[0];
    const float* xyz    = (const float*)d_in[1];
    const float* mask   = (const float*)d_in[2];
    const float* wa     = (const float*)d_in[3];
    const float* wsm    = (const float*)d_in[4];
    const float* compat = (const float*)d_in[5];
    float* outp = (float*)d_out;

    dim3 grid(Wn / TW, Hn / TH, Bsz), blk(BLK);
    crf_fused<<<grid, blk, 0, stream>>>(unary, xyz, mask, wa, wsm, compat, outp);
}

// Round 10
// 127.537 us; speedup vs baseline: 1.2476x; 1.0484x over previous
//
#include <hip/hip_runtime.h>
#include <hip/hip_fp16.h>

#define Bsz 8
#define Cn  4
#define Hn  64
#define Wn  2048
#define HW  (Hn*Wn)          // 131072
#define NPIX (Bsz*HW)        // 1048576

// guard-padded S layout: 2 guard cols each side, 1 guard row top/bottom
#define PW     2052
#define PROWS  66
#define PBATCH (PW*PROWS)    // 135432
#define PTOT   (Bsz*PBATCH)  // 1083456

// Gaussian stencil exp(-(dh^2+dw^2)/(2*0.9^2)), center zeroed.
#define G1 0.53940824f
#define G2 0.29096127f
#define G4 0.08465836f
#define G5 0.04566536f

struct Half4 { __half2 lo, hi; };
struct Half8 { __half2 h[4]; };

__device__ __forceinline__ __half2 bcast_lo(__half2 v) { return __half2half2(__low2half(v)); }
__device__ __forceinline__ __half2 bcast_hi(__half2 v) { return __half2half2(__high2half(v)); }

// ---- pass A: guards + S0=softmax(unary) + iteration-invariant beta*mask ----
__global__ __launch_bounds__(256) void crf_prep(const float* __restrict__ unary,
                                                const float* __restrict__ xyz,
                                                const float* __restrict__ mask,
                                                Half8* __restrict__ BA,
                                                Half8* __restrict__ BB,
                                                Half4* __restrict__ S0,
                                                Half4* __restrict__ S1) {
    int c = blockIdx.x * 256 + threadIdx.x;
    if (c >= PTOT) return;
    int b  = c / PBATCH;
    int rr = c - b * PBATCH;
    int r  = rr / PW;
    int w  = rr - r * PW;
    int hp = r - 1, wp = w - 2;

    Half4 z; z.lo = __float2half2_rn(0.f); z.hi = z.lo;
    if (hp < 0 || hp >= Hn || wp < 0 || wp >= Wn) {   // guard ring of BOTH buffers
        S0[c] = z; S1[c] = z;
        return;
    }

    const size_t pl = (size_t)hp * Wn + wp;
    const size_t qb = (size_t)b * Cn * HW;
    const size_t xb = (size_t)b * 3 * HW;
    const size_t mb = (size_t)b * HW;

    // S0 = softmax(unary)
    float q0 = unary[qb + pl], q1 = unary[qb + pl + HW];
    float q2 = unary[qb + pl + 2 * HW], q3 = unary[qb + pl + 3 * HW];
    float mx = fmaxf(fmaxf(q0, q1), fmaxf(q2, q3));
    float e0 = __expf(q0 - mx), e1 = __expf(q1 - mx);
    float e2 = __expf(q2 - mx), e3 = __expf(q3 - mx);
    float inv = 1.0f / (e0 + e1 + e2 + e3);
    Half4 s; s.lo = __floats2half2_rn(e0 * inv, e1 * inv);
    s.hi = __floats2half2_rn(e2 * inv, e3 * inv);
    S0[c] = s;

    // beta*mask for the 14 taps (clamped reads; clamped values are only ever
    // multiplied by S=0 guard taps, so their content is irrelevant)
    const float xcx = xyz[xb + pl], xcy = xyz[xb + pl + HW], xcz = xyz[xb + pl + 2 * HW];
    float bm[14];
    int t = 0;
#pragma unroll
    for (int dh = -1; dh <= 1; ++dh) {
#pragma unroll
        for (int dw = -2; dw <= 2; ++dw) {
            if (dh == 0 && dw == 0) continue;
            int hn = min(max(hp + dh, 0), Hn - 1);
            int wn = min(max(wp + dw, 0), Wn - 1);
            size_t pn = (size_t)hn * Wn + wn;
            float dx = xyz[xb + pn] - xcx;
            float dy = xyz[xb + pn + HW] - xcy;
            float dz = xyz[xb + pn + 2 * HW] - xcz;
            bm[t++] = __expf(-2222.2222f * (dx * dx + dy * dy + dz * dz)) * mask[mb + pn];
        }
    }
    Half8 a, bv;
    a.h[0] = __floats2half2_rn(bm[0], bm[1]);
    a.h[1] = __floats2half2_rn(bm[2], bm[3]);
    a.h[2] = __floats2half2_rn(bm[4], bm[5]);
    a.h[3] = __floats2half2_rn(bm[6], bm[7]);
    bv.h[0] = __floats2half2_rn(bm[8], bm[9]);
    bv.h[1] = __floats2half2_rn(bm[10], bm[11]);
    bv.h[2] = __floats2half2_rn(bm[12], bm[13]);
    bv.h[3] = __floats2half2_rn(mask[mb + pl], 0.f);
    const size_t pp = mb + pl;       // global unpadded pixel index
    BA[pp] = a;
    BB[pp] = bv;
}

// ---- pass B: one CRF iteration, 1 px/thread, no LDS, no barriers ----
template<bool FINAL>
__global__ __launch_bounds__(256) void crf_pass(const Half4* __restrict__ Sin,
                                                Half4* __restrict__ Sout,
                                                const Half8* __restrict__ BA,
                                                const Half8* __restrict__ BB,
                                                const float* __restrict__ unary,
                                                const float* __restrict__ wa,
                                                const float* __restrict__ wsm,
                                                const float* __restrict__ cw,
                                                float* __restrict__ outp) {
    const int t = blockIdx.x * 256 + threadIdx.x;   // < NPIX (exact grid)
    const int b  = t >> 17;
    const int hw = t & (HW - 1);
    const int h  = hw >> 11;
    const int w  = hw & (Wn - 1);
    const int cc = b * PBATCH + (h + 1) * PW + (w + 2);

    const Half8 ba = BA[t];
    const Half8 bb = BB[t];

    // 14 neighbor taps from padded buffer (guards are zero)
    Half4 s0  = Sin[cc - PW - 2], s1  = Sin[cc - PW - 1], s2  = Sin[cc - PW];
    Half4 s3  = Sin[cc - PW + 1], s4  = Sin[cc - PW + 2];
    Half4 s5  = Sin[cc - 2],      s6  = Sin[cc - 1];
    Half4 s7  = Sin[cc + 1],      s8  = Sin[cc + 2];
    Half4 s9  = Sin[cc + PW - 2], s10 = Sin[cc + PW - 1], s11 = Sin[cc + PW];
    Half4 s12 = Sin[cc + PW + 1], s13 = Sin[cc + PW + 2];

    __half2 kl = __float2half2_rn(0.f), kh = kl, al = kl, ah = kl;

#define TAP(SV, GF, B2) do { \
        const __half2 g2_ = __float2half2_rn(GF); \
        kl = __hfma2(g2_, SV.lo, kl);  kh = __hfma2(g2_, SV.hi, kh); \
        const __half2 b2_ = (B2); \
        al = __hfma2(b2_, SV.lo, al);  ah = __hfma2(b2_, SV.hi, ah); \
    } while (0)

    TAP(s0,  G5, bcast_lo(ba.h[0]));  TAP(s1,  G2, bcast_hi(ba.h[0]));
    TAP(s2,  G1, bcast_lo(ba.h[1]));  TAP(s3,  G2, bcast_hi(ba.h[1]));
    TAP(s4,  G5, bcast_lo(ba.h[2]));
    TAP(s5,  G4, bcast_hi(ba.h[2]));  TAP(s6,  G1, bcast_lo(ba.h[3]));
    TAP(s7,  G1, bcast_hi(ba.h[3]));  TAP(s8,  G4, bcast_lo(bb.h[0]));
    TAP(s9,  G5, bcast_hi(bb.h[0]));  TAP(s10, G2, bcast_lo(bb.h[1]));
    TAP(s11, G1, bcast_hi(bb.h[1]));  TAP(s12, G2, bcast_lo(bb.h[2]));
    TAP(s13, G5, bcast_hi(bb.h[2]));
#undef TAP

    const float ksm[4] = {__low2float(kl), __high2float(kl), __low2float(kh), __high2float(kh)};
    const float app[4] = {__low2float(al), __high2float(al), __low2float(ah), __high2float(ah)};
    const float mc = __half2float(__low2half(bb.h[3]));

    float wk[4];
#pragma unroll
    for (int c = 0; c < 4; ++c)
        wk[c] = ksm[c] * (wsm[c] + wa[c] * (app[c] * mc));

    const size_t qb = (size_t)b * Cn * HW + hw;
    float q[4];
#pragma unroll
    for (int o = 0; o < 4; ++o) {
        float pw = cw[o*4+0]*wk[0] + cw[o*4+1]*wk[1] + cw[o*4+2]*wk[2] + cw[o*4+3]*wk[3];
        q[o] = unary[qb + (size_t)o * HW] - pw;
    }

    if (FINAL) {
#pragma unroll
        for (int o = 0; o < 4; ++o)
            outp[qb + (size_t)o * HW] = q[o];
    } else {
        float mx = fmaxf(fmaxf(q[0], q[1]), fmaxf(q[2], q[3]));
        float e0 = __expf(q[0] - mx), e1 = __expf(q[1] - mx);
        float e2 = __expf(q[2] - mx), e3 = __expf(q[3] - mx);
        float inv = 1.0f / (e0 + e1 + e2 + e3);
        Half4 s; s.lo = __floats2half2_rn(e0 * inv, e1 * inv);
        s.hi = __floats2half2_rn(e2 * inv, e3 * inv);
        Sout[cc] = s;
    }
}

extern "C" void kernel_launch(void* const* d_in, const int* in_sizes, int n_in,
                              void* d_out, int out_size, void* d_ws, size_t ws_size,
                              hipStream_t stream) {
    const float* unary  = (const float*)d_in[0];
    const float* xyz    = (const float*)d_in[1];
    const float* mask   = (const float*)d_in[2];
    const float* wa     = (const float*)d_in[3];
    const float* wsm    = (const float*)d_in[4];
    const float* compat = (const float*)d_in[5];
    float* outp = (float*)d_out;

    char* ws = (char*)d_ws;                          // ws_size = 256 MB
    Half8* BA = (Half8*)ws;                          // 16 MiB
    Half8* BB = (Half8*)(ws + (size_t)NPIX * 16);    // 16 MiB
    Half4* S0 = (Half4*)(ws + (size_t)NPIX * 32);            // 8.67 MiB padded
    Half4* S1 = (Half4*)(ws + (size_t)NPIX * 32 + (size_t)PTOT * 8);

    dim3 blk(256);
    crf_prep<<<dim3((PTOT + 255) / 256), blk, 0, stream>>>(unary, xyz, mask, BA, BB, S0, S1);
    crf_pass<false><<<dim3(NPIX / 256), blk, 0, stream>>>(S0, S1, BA, BB, unary, wa, wsm, compat, nullptr);
    crf_pass<false><<<dim3(NPIX / 256), blk, 0, stream>>>(S1, S0, BA, BB, unary, wa, wsm, compat, nullptr);
    crf_pass<true ><<<dim3(NPIX / 256), blk, 0, stream>>>(S0, nullptr, BA, BB, unary, wa, wsm, compat, outp);
}